// Round 12
// baseline (286.623 us; speedup 1.0000x reference)
//
#include <hip/hip_runtime.h>

#define T_PRIOR 168
#define N_FEAT 11
#define DEC_FEAT 7
#define T_DEC 48
#define BATCH 8192
#define XROW 132                 // u32 words per staged row (8 slots x 16 words + 4 pad)
#define ROWB (XROW*4)            // 528 B
#define BUFB (16*ROWB)           // one chunk buffer
#define HROWW 68                 // sH row stride in words (272 B: 2-way banks, 16B aligned)

typedef __attribute__((ext_vector_type(8))) short short8;
typedef __attribute__((ext_vector_type(4))) float f32x4;
typedef __attribute__((ext_vector_type(4))) int i32x4;

#define MFMA __builtin_amdgcn_mfma_f32_16x16x32_bf16

static __device__ __forceinline__ unsigned fbits(float f){union{float f;unsigned u;}v;v.f=f;return v.u;}
static __device__ __forceinline__ float bitsf(unsigned u){union{unsigned u;float f;}v;v.u=u;return v.f;}
static __device__ __forceinline__ unsigned short bf16rne(float f){
    unsigned x=fbits(f);
    return (unsigned short)((x+0x7fffu+((x>>16)&1u))>>16);
}
static __device__ __forceinline__ float sigm(float x){ return __builtin_amdgcn_rcpf(1.0f + __expf(-x)); }
static __device__ __forceinline__ float tanhf_(float x){ return fmaf(2.0f, __builtin_amdgcn_rcpf(1.0f + __expf(-2.0f*x)), -1.0f); }
static __device__ __forceinline__ short8 s8(i32x4 v){union{i32x4 i;short8 s;}q;q.i=v;return q.s;}
// packed k-pair word: low16 = bf16(lo residual), high16 = bf16(hi); B-weights duplicated per pair
static __device__ __forceinline__ unsigned packw(float x){
    unsigned hi = fbits(x) & 0xffff0000u;
    return hi | (fbits(x - bitsf(hi)) >> 16);
}

__global__ __launch_bounds__(256) __attribute__((amdgpu_waves_per_eu(1,1)))
void gru_dual(const float* __restrict__ prior, const float* __restrict__ teacher,
              const float* __restrict__ eWih, const float* __restrict__ eWhh,
              const float* __restrict__ eBih, const float* __restrict__ eBhh,
              const float* __restrict__ dWih, const float* __restrict__ dWhh,
              const float* __restrict__ dBih, const float* __restrict__ dBhh,
              const float* __restrict__ fcW, const float* __restrict__ fcB,
              float* __restrict__ out)
{
    __shared__ __align__(16) unsigned sHA[16*HROWW];   // group A h, k-paired packw, swizzled
    __shared__ __align__(16) unsigned sHB[16*HROWW];   // group B
    __shared__ __align__(16) unsigned sXA[2*16*XROW];  // staged pre-packed inputs, chunk dbuf
    __shared__ __align__(16) unsigned sXB[2*16*XROW];
    __shared__ __align__(16) float sPA[16][4];         // fc partials [row][u]
    __shared__ __align__(16) float sPB[16][4];

    const int tid  = (int)threadIdx.x;
    const int lane = tid & 63;
    const int u    = tid >> 6;     // wave = unit tile, full K, both groups
    const int c    = lane & 15;    // batch row (in group) / B col
    const int g    = lane >> 4;    // k-group
    const int row0 = (int)blockIdx.x * 32;

    // ---- hoisted addresses ----
    // read: row c, kt-block kt*64, sub-offset g*16 XOR key(c&3)<<4 (contained in 0..63)
    const unsigned hrd = (unsigned)(c*(HROWW*4)) + (((unsigned)(g*16)) ^ (((unsigned)(c&3))<<4));
    unsigned pub[4];
#pragma unroll
    for (int q = 0; q < 4; ++q) {
        int r = g*4 + q;   // batch row written
        pub[q] = (unsigned)(r*(HROWW*4)) + ((((unsigned)(c*4+u))*4) ^ (((unsigned)(r&3))<<4));
    }
    const unsigned rdX = (unsigned)(c*ROWB + g*16);    // + bo + slot*64

    // ---- staging setup ----
    const int srow = tid >> 4, sli = tid & 15;
    int offE[6], offD[4];
#pragma unroll
    for (int n = 0; n < 6; ++n) { int k = sli + 16*n; offE[n] = ((k/11)*16 + (k%11))*4; }
#pragma unroll
    for (int n = 0; n < 4; ++n) { int k = sli + 16*n; offD[n] = ((k/7)*16 + (k%7))*4; }
    const float* gPA = prior   + (size_t)(row0 + srow)     *(T_PRIOR*N_FEAT) + sli;
    const float* gPB = prior   + (size_t)(row0 + 16 + srow)*(T_PRIOR*N_FEAT) + sli;
    const float* gTA = teacher + (size_t)(row0 + srow)     *(T_DEC*DEC_FEAT) + sli;
    const float* gTB = teacher + (size_t)(row0 + 16 + srow)*(T_DEC*DEC_FEAT) + sli;
    char* wrA = (char*)sXA + srow*ROWB;
    char* wrB = (char*)sXB + srow*ROWB;

    // ---- weights (shared by both groups) ----
    short8 BHH[3][4], BIH[3];
    f32x4 bR4, bZ4, bH4, bI4;
    float fwc = 0.0f, fb = 0.0f;

    auto loadPhase = [&](const float* Wih, const float* Whh,
                         const float* bih, const float* bhh, int kv) {
        const int rwb = u*16 + c;
#pragma unroll
        for (int gate = 0; gate < 3; ++gate) {
            const int rw = gate*64 + rwb;
#pragma unroll
            for (int kt = 0; kt < 4; ++kt) {
                union { short8 v; unsigned short s_[8]; } fh;
#pragma unroll
                for (int j = 0; j < 8; ++j) {
                    int k2 = kt*16 + g*4 + (j >> 1);            // k-pair index 0..63
                    int unit = ((k2 & 3) << 4) | (k2 >> 2);     // kappa permutation
                    fh.s_[j] = bf16rne(Whh[rw*64 + unit]);
                }
                BHH[gate][kt] = fh.v;
            }
            union { short8 v; unsigned short s_[8]; } fi;
#pragma unroll
            for (int j = 0; j < 8; ++j) {
                int f = g*4 + (j >> 1);
                fi.s_[j] = (f < kv) ? bf16rne(Wih[rw*kv + f]) : (unsigned short)0;
            }
            BIH[gate] = fi.v;
        }
        const int un = u*16 + c;
        float vR = bih[un] + bhh[un];
        float vZ = bih[64+un] + bhh[64+un];
        float vI = bih[128+un];
        float vH = bhh[128+un];
        bR4 = (f32x4){vR,vR,vR,vR};
        bZ4 = (f32x4){vZ,vZ,vZ,vZ};
        bH4 = (f32x4){vH,vH,vH,vH};
        bI4 = (f32x4){vI,vI,vI,vI};
    };

    f32x4 aAR, aAZ, aAH, aAI;      // group A preacts (live seg1 -> seg2)
    f32x4 aBR, aBZ, aBH, aBI;      // group B preacts (live seg2 -> next seg1)
    float hA[4] = {0,0,0,0}, hB[4] = {0,0,0,0};

    // phase1: read h A-frags + x, 15 MFMA -> preacts
    auto PH1 = [&](const unsigned* sHb, short8 xf,
                   f32x4& R, f32x4& Z, f32x4& H, f32x4& I) {
        const char* hb = (const char*)sHb + hrd;
        short8 a0 = *(const short8*)(hb);
        short8 a1 = *(const short8*)(hb + 64);
        short8 a2 = *(const short8*)(hb + 128);
        short8 a3 = *(const short8*)(hb + 192);
        R = MFMA(a0, BHH[0][0], bR4, 0,0,0);
        R = MFMA(a1, BHH[0][1], R, 0,0,0);
        R = MFMA(a2, BHH[0][2], R, 0,0,0);
        R = MFMA(a3, BHH[0][3], R, 0,0,0);
        R = MFMA(xf, BIH[0],    R, 0,0,0);
        Z = MFMA(a0, BHH[1][0], bZ4, 0,0,0);
        Z = MFMA(a1, BHH[1][1], Z, 0,0,0);
        Z = MFMA(a2, BHH[1][2], Z, 0,0,0);
        Z = MFMA(a3, BHH[1][3], Z, 0,0,0);
        Z = MFMA(xf, BIH[1],    Z, 0,0,0);
        H = MFMA(a0, BHH[2][0], bH4, 0,0,0);
        H = MFMA(a1, BHH[2][1], H, 0,0,0);
        H = MFMA(a2, BHH[2][2], H, 0,0,0);
        H = MFMA(a3, BHH[2][3], H, 0,0,0);
        I = MFMA(xf, BIH[2], bI4, 0,0,0);
    };
    // phase2: gates + h update + publish (packed k-pair u32 per unit)
    auto PH2 = [&](unsigned* sHb, float (&h)[4],
                   f32x4& R, f32x4& Z, f32x4& H, f32x4& I) {
#pragma unroll
        for (int q = 0; q < 4; ++q) {
            float rr = sigm(R[q]);
            float zz = sigm(Z[q]);
            float nn = tanhf_(fmaf(rr, H[q], I[q]));
            float hq = nn + zz*(h[q] - nn);
            h[q] = hq;
            *(unsigned*)((char*)sHb + pub[q]) = packw(hq);
        }
    };
    auto PARTIALS = [&](float (&h)[4], float (*sP)[4]) {
#pragma unroll
        for (int q = 0; q < 4; ++q) {
            float v = h[q] * fwc;
            v += __shfl_xor(v, 1, 64);
            v += __shfl_xor(v, 2, 64);
            v += __shfl_xor(v, 4, 64);
            v += __shfl_xor(v, 8, 64);
            if (c == 0) sP[g*4 + q][u] = v;
        }
    };
    auto RDX = [&](const unsigned* sxb, unsigned bo, int slot) -> i32x4 {
        return *(const i32x4*)((const char*)sxb + (bo + rdX + (unsigned)(slot*64)));
    };
    auto loadE = [&](const float* p, int ch, float (&sv)[6]) {
        const float* s = p + 88*ch;
#pragma unroll
        for (int n = 0; n < 5; ++n) sv[n] = s[16*n];
        sv[5] = (sli < 8) ? s[80] : 0.0f;
    };
    auto writeE = [&](char* wr, unsigned wbo, float (&sv)[6]) {
#pragma unroll
        for (int n = 0; n < 5; ++n) *(unsigned*)(wr + wbo + offE[n]) = packw(sv[n]);
        if (sli < 8) *(unsigned*)(wr + wbo + offE[5]) = packw(sv[5]);
    };
    auto loadD = [&](const float* p, int ch, float (&sv)[4]) {
        const float* s = p + 56*ch;
#pragma unroll
        for (int n = 0; n < 3; ++n) sv[n] = s[16*n];
        sv[3] = (sli < 8) ? s[48] : 0.0f;
    };
    auto writeD = [&](char* wr, unsigned wbo, float (&sv)[4]) {
#pragma unroll
        for (int n = 0; n < 3; ++n) *(unsigned*)(wr + wbo + offD[n]) = packw(sv[n]);
        if (sli < 8) *(unsigned*)(wr + wbo + offD[3]) = packw(sv[3]);
    };

    // ================= prologue =================
    for (int i2 = tid; i2 < 16*HROWW; i2 += 256) { sHA[i2] = 0u; sHB[i2] = 0u; }
    for (int i2 = tid; i2 < 640; i2 += 256) {      // encoder pads: words 11..15
        int r = i2/40, rem = i2%40;
        int idx = r*XROW + (rem/5)*16 + 11 + rem%5;
        sXA[idx] = 0u; sXA[16*XROW + idx] = 0u;
        sXB[idx] = 0u; sXB[16*XROW + idx] = 0u;
    }
    loadPhase(eWih, eWhh, eBih, eBhh, N_FEAT);
    {
        float svA[6], svB[6];
        loadE(gPA, 0, svA); loadE(gPB, 0, svB);
        writeE(wrA, 0, svA); writeE(wrB, 0, svB);
    }
    __syncthreads();

    // ================= encoder: 168 steps, dual-group pipelined =================
    for (int t = 0; t < T_PRIOR; ++t) {
        const int s = t & 7, ch = t >> 3;
        const unsigned bo = (unsigned)((ch & 1)*BUFB), wbo = (unsigned)(((ch+1) & 1)*BUFB);
        const bool st = (s == 0) && (ch < 20);
        float svA[6], svB[6];
        // ---- seg1: phase2_B(t-1) || phase1_A(t) ----
        if (st) { loadE(gPA, ch+1, svA); loadE(gPB, ch+1, svB); }
        i32x4 xA = RDX(sXA, bo, s);
        if (t > 0) PH2(sHB, hB, aBR, aBZ, aBH, aBI);   // publish hB(t)
        PH1(sHA, s8(xA), aAR, aAZ, aAH, aAI);          // preacts A(t)
        __syncthreads();
        // ---- seg2: phase2_A(t) || phase1_B(t) ----
        i32x4 xB = RDX(sXB, bo, s);
        PH2(sHA, hA, aAR, aAZ, aAH, aAI);              // publish hA(t+1)
        PH1(sHB, s8(xB), aBR, aBZ, aBH, aBI);          // preacts B(t)
        if (st) { writeE(wrA, wbo, svA); writeE(wrB, wbo, svB); }
        __syncthreads();
    }

    // ================= transition to decoder =================
    PH2(sHB, hB, aBR, aBZ, aBH, aBI);                  // flush B enc step 167
    loadPhase(dWih, dWhh, dBih, dBhh, DEC_FEAT);
    fwc = fcW[u*16 + c];
    fb  = fcB[0];
    for (int i2 = tid; i2 < 512; i2 += 256) {          // decoder pads: words 7..10
        int r = i2/32, rem = i2%32;
        int idx = r*XROW + (rem/4)*16 + 7 + (rem & 3);
        sXA[idx] = 0u; sXA[16*XROW + idx] = 0u;
        sXB[idx] = 0u; sXB[16*XROW + idx] = 0u;
    }
    {
        float svA[4], svB[4];
        loadD(gTA, 0, svA); loadD(gTB, 0, svB);
        writeD(wrA, 0, svA); writeD(wrB, 0, svB);
    }
    __syncthreads();

    // ================= decoder: 48 steps =================
    for (int i = 0; i < T_DEC; ++i) {
        const int s = i & 7, ch = i >> 3;
        const unsigned bo = (unsigned)((ch & 1)*BUFB), wbo = (unsigned)(((ch+1) & 1)*BUFB);
        const bool st = (s == 0) && (ch < 5);
        float svA[4], svB[4];
        // ---- seg1: phase2_B(i-1)+partials || predA combine+phase1_A(i) ----
        if (st) { loadD(gTA, ch+1, svA); loadD(gTB, ch+1, svB); }
        if (i > 0) {
            PH2(sHB, hB, aBR, aBZ, aBH, aBI);          // B completes step i-1
            PARTIALS(hB, sPB);
        }
        i32x4 xA = RDX(sXA, bo, s);
        if (i > 0) {
            f32x4 pp = *(const f32x4*)&sPA[c][0];      // partials_A(i-1), barrier-protected
            float predA = pp[0] + pp[1] + pp[2] + pp[3] + fb;
            if (g == 1) xA[0] = (int)packw(predA);     // feature-4 k-pair patch
            if (u == 0 && g == 0) out[(size_t)(row0 + c)*T_DEC + (i - 1)] = predA;
        }
        PH1(sHA, s8(xA), aAR, aAZ, aAH, aAI);
        __syncthreads();
        // ---- seg2: phase2_A(i)+partials || predB combine+phase1_B(i) ----
        PH2(sHA, hA, aAR, aAZ, aAH, aAI);              // A completes step i
        PARTIALS(hA, sPA);
        i32x4 xB = RDX(sXB, bo, s);
        if (i > 0) {
            f32x4 pp = *(const f32x4*)&sPB[c][0];      // partials_B(i-1), mid-barrier-protected
            float predB = pp[0] + pp[1] + pp[2] + pp[3] + fb;
            if (g == 1) xB[0] = (int)packw(predB);
            if (u == 0 && g == 0) out[(size_t)(row0 + 16 + c)*T_DEC + (i - 1)] = predB;
        }
        PH1(sHB, s8(xB), aBR, aBZ, aBH, aBI);
        if (st) { writeD(wrA, wbo, svA); writeD(wrB, wbo, svB); }
        __syncthreads();
    }

    // ================= epilogue =================
    PH2(sHB, hB, aBR, aBZ, aBH, aBI);                  // B completes step 47
    PARTIALS(hB, sPB);
    {
        f32x4 pp = *(const f32x4*)&sPA[c][0];          // A step-47 partials (barrier passed)
        float predA = pp[0] + pp[1] + pp[2] + pp[3] + fb;
        if (u == 0 && g == 0) out[(size_t)(row0 + c)*T_DEC + (T_DEC - 1)] = predA;
    }
    __syncthreads();
    {
        f32x4 pp = *(const f32x4*)&sPB[c][0];
        float predB = pp[0] + pp[1] + pp[2] + pp[3] + fb;
        if (u == 0 && g == 0) out[(size_t)(row0 + 16 + c)*T_DEC + (T_DEC - 1)] = predB;
    }
}

extern "C" void kernel_launch(void* const* d_in, const int* in_sizes, int n_in,
                              void* d_out, int out_size, void* d_ws, size_t ws_size,
                              hipStream_t stream)
{
    const float* prior   = (const float*)d_in[0];
    const float* teacher = (const float*)d_in[1];
    const float* eWih    = (const float*)d_in[2];
    const float* eWhh    = (const float*)d_in[3];
    const float* eBih    = (const float*)d_in[4];
    const float* eBhh    = (const float*)d_in[5];
    const float* dWih    = (const float*)d_in[6];
    const float* dWhh    = (const float*)d_in[7];
    const float* dBih    = (const float*)d_in[8];
    const float* dBhh    = (const float*)d_in[9];
    const float* fcW     = (const float*)d_in[10];
    const float* fcB     = (const float*)d_in[11];
    float* out = (float*)d_out;

    dim3 grid(BATCH / 32);    // 256 blocks x 4 waves x 32 rows (2 groups of 16)
    dim3 block(256);
    hipLaunchKernelGGL(gru_dual, grid, block, 0, stream,
                       prior, teacher, eWih, eWhh, eBih, eBhh,
                       dWih, dWhh, dBih, dBhh, fcW, fcB, out);
}

// Round 13
// 159.091 us; speedup vs baseline: 1.8016x; 1.8016x over previous
//
#include <hip/hip_runtime.h>

#define T_PRIOR 168
#define N_FEAT 11
#define DEC_FEAT 7
#define T_DEC 48
#define BATCH 8192
#define XROWU 136                // ushorts per staged row: 8 slots x 16 + 8-ushort zero pad (272 B, 2-way banks)
#define ROWB (XROWU*2)           // 272 B
#define BUFB (16*ROWB)           // 4352 B per chunk buffer

typedef __attribute__((ext_vector_type(8))) short short8;
typedef __attribute__((ext_vector_type(4))) float f32x4;
typedef __attribute__((ext_vector_type(4))) int i32x4;

#define MFMA __builtin_amdgcn_mfma_f32_16x16x32_bf16

static __device__ __forceinline__ unsigned fbits(float f){union{float f;unsigned u;}v;v.f=f;return v.u;}
static __device__ __forceinline__ unsigned short bf16rne(float f){
    unsigned x=fbits(f);
    return (unsigned short)((x+0x7fffu+((x>>16)&1u))>>16);
}
static __device__ __forceinline__ float sigm(float x){ return __builtin_amdgcn_rcpf(1.0f + __expf(-x)); }
static __device__ __forceinline__ float tanhf_(float x){ return fmaf(2.0f, __builtin_amdgcn_rcpf(1.0f + __expf(-2.0f*x)), -1.0f); }
static __device__ __forceinline__ short8 s8(i32x4 v){union{i32x4 i;short8 s;}q;q.i=v;return q.s;}

__global__ __launch_bounds__(256) __attribute__((amdgpu_waves_per_eu(2,2)))
void gru_mfma(const float* __restrict__ prior, const float* __restrict__ teacher,
              const float* __restrict__ eWih, const float* __restrict__ eWhh,
              const float* __restrict__ eBih, const float* __restrict__ eBhh,
              const float* __restrict__ dWih, const float* __restrict__ dWhh,
              const float* __restrict__ dBih, const float* __restrict__ dBhh,
              const float* __restrict__ fcW, const float* __restrict__ fcB,
              float* __restrict__ out)
{
    __shared__ __align__(16) unsigned short sH[2][1024];   // [parity][16 rows x 64 kappa] bf16, swizzled
    __shared__ __align__(16) unsigned short sX[2*16*XROWU];// staged bf16 inputs, chunk dbuf
    __shared__ __align__(16) float sPartial[2][16][4];     // [parity][row][u]

    const int tid  = (int)threadIdx.x;
    const int lane = tid & 63;
    const int u    = tid >> 6;       // wave = unit tile (full K per wave)
    const int c    = lane & 15;      // batch row / B col
    const int g    = lane >> 4;      // k-group
    const int row0 = (int)blockIdx.x * 16;

    // ---- sH fragment offsets (kappa layout, XOR-swizzled; R8-proven) ----
    const unsigned cs = ((unsigned)(c & 7)) << 4;
    const unsigned rbA0 = (unsigned)(c*128) + (((unsigned)(g*16)) ^ cs);       // K 0..31
    const unsigned rbA1 = (unsigned)(c*128) + (((unsigned)(64 + g*16)) ^ cs);  // K 32..63
    unsigned pubOff[4];
#pragma unroll
    for (int q = 0; q < 4; ++q) {
        int r = g*4 + q;
        pubOff[q] = (unsigned)(r*128) + (((unsigned)(c*8 + u*2)) ^ (((unsigned)(r&7))<<4));
    }

    // ---- x read offsets: g-groups beyond the valid features read the zeroed 16B row pad ----
    const unsigned xRowB = (unsigned)(c*ROWB);
    const unsigned xE_off = (g < 2) ? (unsigned)(g*16) : 256u;   // enc: g0 feats0-7, g1 feats8-15(pad), g2/3 zero-pad
    const unsigned xE_mul = (g < 2) ? 32u : 0u;
    const unsigned xD_off = (g == 0) ? 0u : 256u;                // dec: g0 feats0-7 (f7 zero), g1-3 zero-pad
    const unsigned xD_mul = (g == 0) ? 32u : 0u;
    char* sXB = (char*)sX;

    // ---- staging setup (all 256 threads) ----
    const int srow = tid >> 4, sli = tid & 15;
    char* sXwr = sXB + srow*ROWB;
    int offE[6], offD[4];   // byte offsets within row for staged elements
#pragma unroll
    for (int n = 0; n < 6; ++n) { int k = sli + 16*n; offE[n] = ((k/11)*16 + (k%11))*2; }
#pragma unroll
    for (int n = 0; n < 4; ++n) { int k = sli + 16*n; offD[n] = ((k/7)*16 + (k%7))*2; }
    const float* gP = prior   + (size_t)(row0 + srow)*(T_PRIOR*N_FEAT) + sli;
    const float* gT = teacher + (size_t)(row0 + srow)*(T_DEC*DEC_FEAT) + sli;

    // ---- per-wave weights (full K, single bf16) ----
    short8 BHH[3][2], BIH[3];
    f32x4 bR4, bZ4, bH4, bI4;
    auto loadPhase = [&](const float* Wih, const float* Whh,
                         const float* bih, const float* bhh, int kvalid) {
        const int rwb = u*16 + c;
#pragma unroll
        for (int gate = 0; gate < 3; ++gate) {
            const int rw = gate*64 + rwb;
#pragma unroll
            for (int kt = 0; kt < 2; ++kt) {
                union { short8 v; unsigned short s[8]; } fh;
#pragma unroll
                for (int j = 0; j < 8; ++j) {
                    int kap = kt*32 + g*8 + j;
                    int unit = ((kap & 3) << 4) | (kap >> 2);   // kappa permutation
                    fh.s[j] = bf16rne(Whh[rw*64 + unit]);
                }
                BHH[gate][kt] = fh.v;
            }
            union { short8 v; unsigned short s[8]; } fi;
#pragma unroll
            for (int j = 0; j < 8; ++j) {
                int k = g*8 + j;
                fi.s[j] = (k < kvalid) ? bf16rne(Wih[rw*kvalid + k]) : (unsigned short)0;
            }
            BIH[gate] = fi.v;
        }
        const int un = u*16 + c;
        float vR = bih[un] + bhh[un];
        float vZ = bih[64+un] + bhh[64+un];
        float vI = bih[128+un];
        float vH = bhh[128+un];
        bR4 = (f32x4){vR,vR,vR,vR};
        bZ4 = (f32x4){vZ,vZ,vZ,vZ};
        bH4 = (f32x4){vH,vH,vH,vH};
        bI4 = (f32x4){vI,vI,vI,vI};
    };

    float h[4] = {0.0f, 0.0f, 0.0f, 0.0f};

    // one GRU step: read h(p) frags, 9 MFMA, gates, publish bf16 h into p^1
    auto gru_step = [&](int p, short8 xf) {
        const char* hb = (const char*)&sH[p][0];
        short8 a0 = *(const short8*)(hb + rbA0);
        short8 a1 = *(const short8*)(hb + rbA1);

        f32x4 R = MFMA(a0, BHH[0][0], bR4, 0,0,0);
        R = MFMA(a1, BHH[0][1], R, 0,0,0);
        R = MFMA(xf, BIH[0],    R, 0,0,0);
        f32x4 Z = MFMA(a0, BHH[1][0], bZ4, 0,0,0);
        Z = MFMA(a1, BHH[1][1], Z, 0,0,0);
        Z = MFMA(xf, BIH[1],    Z, 0,0,0);
        f32x4 Hh = MFMA(a0, BHH[2][0], bH4, 0,0,0);
        Hh = MFMA(a1, BHH[2][1], Hh, 0,0,0);
        f32x4 I = MFMA(xf, BIH[2], bI4, 0,0,0);

        char* hw = (char*)&sH[p^1][0];
#pragma unroll
        for (int q = 0; q < 4; ++q) {
            float rr = sigm(R[q]);
            float zz = sigm(Z[q]);
            float nn = tanhf_(fmaf(rr, Hh[q], I[q]));
            float hq = nn + zz*(h[q] - nn);
            h[q] = hq;
            *(unsigned short*)(hw + pubOff[q]) = bf16rne(hq);   // f32 state stays in registers;
        }                                                        // bf16 rounding = fresh noise only
    };

    // ---------------- prologue ----------------
    {   // h(0) = 0 into parity-0 buffer
        unsigned* z0 = (unsigned*)&sH[0][0];
#pragma unroll
        for (int it = 0; it < 2; ++it) z0[tid + 256*it] = 0u;
    }
    // zero encoder pad ushorts: f=11..15 per slot (640/buf) + row pad 128..135 (128/buf), both buffers
#pragma unroll
    for (int it = 0; it < 6; ++it) {
        int e = tid + 256*it;
        int b = e / 768, rem = e % 768;
        int idx;
        if (rem < 640) {
            int r = rem / 40, q2 = rem % 40;
            idx = b*(16*XROWU) + r*XROWU + (q2/5)*16 + 11 + q2%5;
        } else {
            int rem2 = rem - 640;
            idx = b*(16*XROWU) + (rem2 >> 3)*XROWU + 128 + (rem2 & 7);
        }
        sX[idx] = 0;
    }
    loadPhase(eWih, eWhh, eBih, eBhh, N_FEAT);
    {   // stage encoder chunk 0 (bf16)
        float sv[6];
#pragma unroll
        for (int n = 0; n < 5; ++n) sv[n] = gP[16*n];
        sv[5] = (sli < 8) ? gP[80] : 0.0f;
#pragma unroll
        for (int n = 0; n < 5; ++n) *(unsigned short*)(sXwr + offE[n]) = bf16rne(sv[n]);
        if (sli < 8) *(unsigned short*)(sXwr + offE[5]) = bf16rne(sv[5]);
    }

    // ---------------- encoder: 21 chunks x 8 steps ----------------
    for (int ch = 0; ch < 21; ++ch) {
        const unsigned bo  = (unsigned)((ch & 1) * BUFB);
        const unsigned wbo = (unsigned)(((ch + 1) & 1) * BUFB);
        const bool st = (ch < 20);
        float sv[6];
#pragma unroll
        for (int s = 0; s < 8; ++s) {
            __syncthreads();
            if (s == 0 && st) {              // issue next-chunk loads (full-chunk latency cover)
                const float* sp = gP + 88*(ch+1);
#pragma unroll
                for (int n = 0; n < 5; ++n) sv[n] = sp[16*n];
                sv[5] = (sli < 8) ? sp[80] : 0.0f;
            }
            short8 xf = *(const short8*)(sXB + (bo + xRowB + xE_off + (unsigned)s*xE_mul));
            gru_step(s & 1, xf);
            if (s == 0 && st) {              // write staged chunk to the other buffer
#pragma unroll
                for (int n = 0; n < 5; ++n) *(unsigned short*)(sXwr + wbo + offE[n]) = bf16rne(sv[n]);
                if (sli < 8) *(unsigned short*)(sXwr + wbo + offE[5]) = bf16rne(sv[5]);
            }
        }
    }

    // ---------------- decoder setup ----------------
    __syncthreads();   // all encoder sX reads done before pad rewrites
    loadPhase(dWih, dWhh, dBih, dBhh, DEC_FEAT);
    const float fwc = fcW[u*16 + c];
    const float fb  = fcB[0];
    // zero decoder pad ushorts f=7..15 (1152/buf; row pad already zero), both buffers
#pragma unroll
    for (int it = 0; it < 9; ++it) {
        int e = tid + 256*it;
        int b = e / 1152, rem = e % 1152;
        int r = rem / 72, q2 = rem % 72;
        sX[b*(16*XROWU) + r*XROWU + (q2/9)*16 + 7 + q2%9] = 0;
    }
    {   // stage decoder chunk 0
        float sv[4];
#pragma unroll
        for (int n = 0; n < 3; ++n) sv[n] = gT[16*n];
        sv[3] = (sli < 8) ? gT[48] : 0.0f;
#pragma unroll
        for (int n = 0; n < 3; ++n) *(unsigned short*)(sXwr + offD[n]) = bf16rne(sv[n]);
        if (sli < 8) *(unsigned short*)(sXwr + offD[3]) = bf16rne(sv[3]);
    }

    // ---------------- decoder: 6 chunks x 8 steps ----------------
    for (int ch = 0; ch < 6; ++ch) {
        const unsigned bo  = (unsigned)((ch & 1) * BUFB);
        const unsigned wbo = (unsigned)(((ch + 1) & 1) * BUFB);
        const bool st = (ch < 5);
        float sv[4];
#pragma unroll
        for (int s = 0; s < 8; ++s) {
            const int i = ch*8 + s;
            __syncthreads();
            if (s == 0 && st) {
                const float* sp = gT + 56*(ch+1);
#pragma unroll
                for (int n = 0; n < 3; ++n) sv[n] = sp[16*n];
                sv[3] = (sli < 8) ? sp[48] : 0.0f;
            }
            const bool hasPred = (s > 0) || (ch > 0);
            i32x4 xi = *(const i32x4*)(sXB + (bo + xRowB + xD_off + (unsigned)s*xD_mul));
            if (hasPred) {                    // pred_{i-1} from parity (s&1)^1 partials
                f32x4 pp = *(const f32x4*)&sPartial[(s & 1) ^ 1][c][0];
                float pred = pp[0] + pp[1] + pp[2] + pp[3] + fb;
                if (g == 0)                   // feature 4 = ushort #4 = word2 low half
                    xi[2] = (int)(((unsigned)xi[2] & 0xffff0000u) | (unsigned)bf16rne(pred));
                if (u == 0 && g == 0)
                    out[(size_t)(row0 + c)*T_DEC + (i - 1)] = pred;
            }
            gru_step(s & 1, s8(xi));
            // fc partials over this wave's 16 units
#pragma unroll
            for (int q = 0; q < 4; ++q) {
                float v = h[q] * fwc;
                v += __shfl_xor(v, 1, 64);
                v += __shfl_xor(v, 2, 64);
                v += __shfl_xor(v, 4, 64);
                v += __shfl_xor(v, 8, 64);
                if (c == 0) sPartial[s & 1][g*4 + q][u] = v;
            }
            if (s == 0 && st) {
#pragma unroll
                for (int n = 0; n < 3; ++n) *(unsigned short*)(sXwr + wbo + offD[n]) = bf16rne(sv[n]);
                if (sli < 8) *(unsigned short*)(sXwr + wbo + offD[3]) = bf16rne(sv[3]);
            }
        }
    }
    __syncthreads();
    if (u == 0 && g == 0) {   // final pred (i = 47, parity 1)
        f32x4 pp = *(const f32x4*)&sPartial[1][c][0];
        float pred = pp[0] + pp[1] + pp[2] + pp[3] + fb;
        out[(size_t)(row0 + c)*T_DEC + (T_DEC - 1)] = pred;
    }
}

extern "C" void kernel_launch(void* const* d_in, const int* in_sizes, int n_in,
                              void* d_out, int out_size, void* d_ws, size_t ws_size,
                              hipStream_t stream)
{
    const float* prior   = (const float*)d_in[0];
    const float* teacher = (const float*)d_in[1];
    const float* eWih    = (const float*)d_in[2];
    const float* eWhh    = (const float*)d_in[3];
    const float* eBih    = (const float*)d_in[4];
    const float* eBhh    = (const float*)d_in[5];
    const float* dWih    = (const float*)d_in[6];
    const float* dWhh    = (const float*)d_in[7];
    const float* dBih    = (const float*)d_in[8];
    const float* dBhh    = (const float*)d_in[9];
    const float* fcW     = (const float*)d_in[10];
    const float* fcB     = (const float*)d_in[11];
    float* out = (float*)d_out;

    dim3 grid(BATCH / 16);    // 512 blocks x 4 waves (full-K per wave, 1 barrier/step)
    dim3 block(256);
    hipLaunchKernelGGL(gru_mfma, grid, block, 0, stream,
                       prior, teacher, eWih, eWhh, eBih, eBhh,
                       dWih, dWhh, dBih, dBhh, fcW, fcB, out);
}

// Round 14
// 155.994 us; speedup vs baseline: 1.8374x; 1.0199x over previous
//
#include <hip/hip_runtime.h>

#define T_PRIOR 168
#define N_FEAT 11
#define DEC_FEAT 7
#define T_DEC 48
#define BATCH 8192
#define XROWU 136                // ushorts per staged row: 8 slots x 16 + 8-ushort zero pad (272 B)
#define ROWB (XROWU*2)           // 272 B
#define BUFB (16*ROWB)           // 4352 B per chunk buffer

typedef __attribute__((ext_vector_type(8))) short short8;
typedef __attribute__((ext_vector_type(4))) float f32x4;
typedef __attribute__((ext_vector_type(4))) int i32x4;

#define MFMA __builtin_amdgcn_mfma_f32_16x16x32_bf16

static __device__ __forceinline__ unsigned fbits(float f){union{float f;unsigned u;}v;v.f=f;return v.u;}
static __device__ __forceinline__ unsigned short bf16rne(float f){
    unsigned x=fbits(f);
    return (unsigned short)((x+0x7fffu+((x>>16)&1u))>>16);
}
static __device__ __forceinline__ float sigm(float x){ return __builtin_amdgcn_rcpf(1.0f + __expf(-x)); }
static __device__ __forceinline__ float tanhf_(float x){ return fmaf(2.0f, __builtin_amdgcn_rcpf(1.0f + __expf(-2.0f*x)), -1.0f); }
static __device__ __forceinline__ short8 s8(i32x4 v){union{i32x4 i;short8 s;}q;q.i=v;return q.s;}

__global__ __launch_bounds__(256) __attribute__((amdgpu_waves_per_eu(2,2)))
void gru_mfma(const float* __restrict__ prior, const float* __restrict__ teacher,
              const float* __restrict__ eWih, const float* __restrict__ eWhh,
              const float* __restrict__ eBih, const float* __restrict__ eBhh,
              const float* __restrict__ dWih, const float* __restrict__ dWhh,
              const float* __restrict__ dBih, const float* __restrict__ dBhh,
              const float* __restrict__ fcW, const float* __restrict__ fcB,
              float* __restrict__ out)
{
    __shared__ __align__(16) unsigned short sH[2][1024];   // [parity][16 rows x 64 kappa] bf16, swizzled
    __shared__ __align__(16) unsigned short sX[2*16*XROWU];// staged bf16 inputs, chunk dbuf
    __shared__ __align__(16) float sPartial[2][16][4];     // [parity][row][u]

    const int tid  = (int)threadIdx.x;
    const int lane = tid & 63;
    const int u    = tid >> 6;       // wave = unit tile (full K per wave)
    const int c    = lane & 15;      // batch row / B col
    const int g    = lane >> 4;      // k-group
    const int row0 = (int)blockIdx.x * 16;

    // ---- sH fragment offsets (kappa layout, XOR-swizzled; R8/R13-proven) ----
    const unsigned cs = ((unsigned)(c & 7)) << 4;
    const unsigned rbA0 = (unsigned)(c*128) + (((unsigned)(g*16)) ^ cs);       // K 0..31
    const unsigned rbA1 = (unsigned)(c*128) + (((unsigned)(64 + g*16)) ^ cs);  // K 32..63
    unsigned pubOff[4];
#pragma unroll
    for (int q = 0; q < 4; ++q) {
        int r = g*4 + q;
        pubOff[q] = (unsigned)(r*128) + (((unsigned)(c*8 + u*2)) ^ (((unsigned)(r&7))<<4));
    }

    // ---- x read offsets: g-groups beyond the valid features read the zeroed 16B row pad ----
    const unsigned xRowB = (unsigned)(c*ROWB);
    const unsigned xE_off = (g < 2) ? (unsigned)(g*16) : 256u;
    const unsigned xE_mul = (g < 2) ? 32u : 0u;
    const unsigned xD_off = (g == 0) ? 0u : 256u;
    const unsigned xD_mul = (g == 0) ? 32u : 0u;
    char* sXB = (char*)sX;

    // ---- staging setup (all 256 threads) ----
    const int srow = tid >> 4, sli = tid & 15;
    char* sXwr = sXB + srow*ROWB;
    int offE[6], offD[4];
#pragma unroll
    for (int n = 0; n < 6; ++n) { int k = sli + 16*n; offE[n] = ((k/11)*16 + (k%11))*2; }
#pragma unroll
    for (int n = 0; n < 4; ++n) { int k = sli + 16*n; offD[n] = ((k/7)*16 + (k%7))*2; }
    const float* gP = prior   + (size_t)(row0 + srow)*(T_PRIOR*N_FEAT) + sli;
    const float* gT = teacher + (size_t)(row0 + srow)*(T_DEC*DEC_FEAT) + sli;

    // ---- per-wave weights (full K, single bf16) ----
    short8 BHH[3][2], BIH[3];
    f32x4 bR4, bZ4, bH4, bI4;
    auto loadPhase = [&](const float* Wih, const float* Whh,
                         const float* bih, const float* bhh, int kvalid) {
        const int rwb = u*16 + c;
#pragma unroll
        for (int gate = 0; gate < 3; ++gate) {
            const int rw = gate*64 + rwb;
#pragma unroll
            for (int kt = 0; kt < 2; ++kt) {
                union { short8 v; unsigned short s[8]; } fh;
#pragma unroll
                for (int j = 0; j < 8; ++j) {
                    int kap = kt*32 + g*8 + j;
                    int unit = ((kap & 3) << 4) | (kap >> 2);   // kappa permutation
                    fh.s[j] = bf16rne(Whh[rw*64 + unit]);
                }
                BHH[gate][kt] = fh.v;
            }
            union { short8 v; unsigned short s[8]; } fi;
#pragma unroll
            for (int j = 0; j < 8; ++j) {
                int k = g*8 + j;
                fi.s[j] = (k < kvalid) ? bf16rne(Wih[rw*kvalid + k]) : (unsigned short)0;
            }
            BIH[gate] = fi.v;
        }
        const int un = u*16 + c;
        float vR = bih[un] + bhh[un];
        float vZ = bih[64+un] + bhh[64+un];
        float vI = bih[128+un];
        float vH = bhh[128+un];
        bR4 = (f32x4){vR,vR,vR,vR};
        bZ4 = (f32x4){vZ,vZ,vZ,vZ};
        bH4 = (f32x4){vH,vH,vH,vH};
        bI4 = (f32x4){vI,vI,vI,vI};
    };

    float h[4] = {0.0f, 0.0f, 0.0f, 0.0f};

    // hoisted x-part: 3 MFMAs with bias C-in, independent of sH (issued pre-barrier)
    f32x4 xR, xZ, xI;
    auto xpart = [&](short8 xf) {
        xR = MFMA(xf, BIH[0], bR4, 0,0,0);
        xZ = MFMA(xf, BIH[1], bZ4, 0,0,0);
        xI = MFMA(xf, BIH[2], bI4, 0,0,0);
    };

    // post-barrier: 2 ds_read + 6 hh-MFMAs (2-deep chains, C-in = hoisted x-part), gates, publish
    auto hh_step = [&](int p) {
        const char* hb = (const char*)&sH[p][0];
        short8 a0 = *(const short8*)(hb + rbA0);
        short8 a1 = *(const short8*)(hb + rbA1);
        __builtin_amdgcn_s_setprio(1);
        f32x4 R = MFMA(a0, BHH[0][0], xR, 0,0,0);
        R = MFMA(a1, BHH[0][1], R, 0,0,0);
        f32x4 Z = MFMA(a0, BHH[1][0], xZ, 0,0,0);
        Z = MFMA(a1, BHH[1][1], Z, 0,0,0);
        f32x4 Hh = MFMA(a0, BHH[2][0], bH4, 0,0,0);
        Hh = MFMA(a1, BHH[2][1], Hh, 0,0,0);
        __builtin_amdgcn_s_setprio(0);
        char* hw = (char*)&sH[p^1][0];
#pragma unroll
        for (int q = 0; q < 4; ++q) {
            float rr = sigm(R[q]);
            float zz = sigm(Z[q]);
            float nn = tanhf_(fmaf(rr, Hh[q], xI[q]));
            float hq = nn + zz*(h[q] - nn);
            h[q] = hq;
            *(unsigned short*)(hw + pubOff[q]) = bf16rne(hq);
        }
    };

    // full 9-MFMA step (decoder path, R13-verbatim: x MFMAs post-barrier, after pred patch)
    auto gru_step = [&](int p, short8 xf) {
        const char* hb = (const char*)&sH[p][0];
        short8 a0 = *(const short8*)(hb + rbA0);
        short8 a1 = *(const short8*)(hb + rbA1);
        f32x4 R = MFMA(a0, BHH[0][0], bR4, 0,0,0);
        R = MFMA(a1, BHH[0][1], R, 0,0,0);
        R = MFMA(xf, BIH[0],    R, 0,0,0);
        f32x4 Z = MFMA(a0, BHH[1][0], bZ4, 0,0,0);
        Z = MFMA(a1, BHH[1][1], Z, 0,0,0);
        Z = MFMA(xf, BIH[1],    Z, 0,0,0);
        f32x4 Hh = MFMA(a0, BHH[2][0], bH4, 0,0,0);
        Hh = MFMA(a1, BHH[2][1], Hh, 0,0,0);
        f32x4 I = MFMA(xf, BIH[2], bI4, 0,0,0);
        char* hw = (char*)&sH[p^1][0];
#pragma unroll
        for (int q = 0; q < 4; ++q) {
            float rr = sigm(R[q]);
            float zz = sigm(Z[q]);
            float nn = tanhf_(fmaf(rr, Hh[q], I[q]));
            float hq = nn + zz*(h[q] - nn);
            h[q] = hq;
            *(unsigned short*)(hw + pubOff[q]) = bf16rne(hq);
        }
    };

    // ---------------- prologue ----------------
    {   // h(0) = 0 into parity-0 buffer
        unsigned* z0 = (unsigned*)&sH[0][0];
#pragma unroll
        for (int it = 0; it < 2; ++it) z0[tid + 256*it] = 0u;
    }
    // zero encoder pad ushorts: f=11..15 per slot (640/buf) + row pad 128..135 (128/buf), both buffers
#pragma unroll
    for (int it = 0; it < 6; ++it) {
        int e = tid + 256*it;
        int b = e / 768, rem = e % 768;
        int idx;
        if (rem < 640) {
            int r = rem / 40, q2 = rem % 40;
            idx = b*(16*XROWU) + r*XROWU + (q2/5)*16 + 11 + q2%5;
        } else {
            int rem2 = rem - 640;
            idx = b*(16*XROWU) + (rem2 >> 3)*XROWU + 128 + (rem2 & 7);
        }
        sX[idx] = 0;
    }
    loadPhase(eWih, eWhh, eBih, eBhh, N_FEAT);
    {   // stage encoder chunk 0 (bf16)
        float sv[6];
#pragma unroll
        for (int n = 0; n < 5; ++n) sv[n] = gP[16*n];
        sv[5] = (sli < 8) ? gP[80] : 0.0f;
#pragma unroll
        for (int n = 0; n < 5; ++n) *(unsigned short*)(sXwr + offE[n]) = bf16rne(sv[n]);
        if (sli < 8) *(unsigned short*)(sXwr + offE[5]) = bf16rne(sv[5]);
    }
    __syncthreads();   // chunk-0 visible before the xf(0) prefetch read
    {
        short8 xf0 = *(const short8*)(sXB + (xRowB + xE_off));
        xpart(xf0);
    }

    // ---------------- encoder: 21 chunks x 8 steps, x-part hoisted ----------------
    for (int ch = 0; ch < 21; ++ch) {
        const unsigned wbo = (unsigned)(((ch + 1) & 1) * BUFB);
        const bool st = (ch < 20);
        float sv[6];
#pragma unroll
        for (int s = 0; s < 8; ++s) {
            const int t = ch*8 + s;
            __syncthreads();
            if (s == 0 && st) {              // issue next-chunk loads (full-chunk latency cover)
                const float* sp = gP + 88*(ch+1);
#pragma unroll
                for (int n = 0; n < 5; ++n) sv[n] = sp[16*n];
                sv[5] = (sli < 8) ? sp[80] : 0.0f;
            }
            hh_step(t & 1);                  // critical path: 2 ds_read + 6 MFMA + gates
            if (s == 0 && st) {              // write staged chunk to the other buffer
#pragma unroll
                for (int n = 0; n < 5; ++n) *(unsigned short*)(sXwr + wbo + offE[n]) = bf16rne(sv[n]);
                if (sli < 8) *(unsigned short*)(sXwr + wbo + offE[5]) = bf16rne(sv[5]);
            }
            if (t < T_PRIOR - 1) {           // prefetch x(t+1) + hoisted x-MFMAs (pre-barrier)
                const int tn = t + 1;
                const unsigned nbo = (unsigned)(((tn >> 3) & 1) * BUFB);
                short8 xf = *(const short8*)(sXB + (nbo + xRowB + xE_off + (unsigned)(tn & 7)*xE_mul));
                xpart(xf);
            }
        }
    }

    // ---------------- decoder setup ----------------
    __syncthreads();   // all encoder sX reads done before pad rewrites
    loadPhase(dWih, dWhh, dBih, dBhh, DEC_FEAT);
    const float fwc = fcW[u*16 + c];
    const float fb  = fcB[0];
    // zero decoder pad ushorts f=7..15 (1152/buf), both buffers
#pragma unroll
    for (int it = 0; it < 9; ++it) {
        int e = tid + 256*it;
        int b = e / 1152, rem = e % 1152;
        int r = rem / 72, q2 = rem % 72;
        sX[b*(16*XROWU) + r*XROWU + (q2/9)*16 + 7 + q2%9] = 0;
    }
    {   // stage decoder chunk 0
        float sv[4];
#pragma unroll
        for (int n = 0; n < 3; ++n) sv[n] = gT[16*n];
        sv[3] = (sli < 8) ? gT[48] : 0.0f;
#pragma unroll
        for (int n = 0; n < 3; ++n) *(unsigned short*)(sXwr + offD[n]) = bf16rne(sv[n]);
        if (sli < 8) *(unsigned short*)(sXwr + offD[3]) = bf16rne(sv[3]);
    }

    // ---------------- decoder: 6 chunks x 8 steps (R13-verbatim) ----------------
    for (int ch = 0; ch < 6; ++ch) {
        const unsigned bo  = (unsigned)((ch & 1) * BUFB);
        const unsigned wbo = (unsigned)(((ch + 1) & 1) * BUFB);
        const bool st = (ch < 5);
        float sv[4];
#pragma unroll
        for (int s = 0; s < 8; ++s) {
            const int i = ch*8 + s;
            __syncthreads();
            if (s == 0 && st) {
                const float* sp = gT + 56*(ch+1);
#pragma unroll
                for (int n = 0; n < 3; ++n) sv[n] = sp[16*n];
                sv[3] = (sli < 8) ? sp[48] : 0.0f;
            }
            const bool hasPred = (s > 0) || (ch > 0);
            i32x4 xi = *(const i32x4*)(sXB + (bo + xRowB + xD_off + (unsigned)s*xD_mul));
            if (hasPred) {                    // pred_{i-1} from parity (s&1)^1 partials
                f32x4 pp = *(const f32x4*)&sPartial[(s & 1) ^ 1][c][0];
                float pred = pp[0] + pp[1] + pp[2] + pp[3] + fb;
                if (g == 0)                   // feature 4 = ushort #4 = word2 low half
                    xi[2] = (int)(((unsigned)xi[2] & 0xffff0000u) | (unsigned)bf16rne(pred));
                if (u == 0 && g == 0)
                    out[(size_t)(row0 + c)*T_DEC + (i - 1)] = pred;
            }
            gru_step(s & 1, s8(xi));
            // fc partials over this wave's 16 units
#pragma unroll
            for (int q = 0; q < 4; ++q) {
                float v = h[q] * fwc;
                v += __shfl_xor(v, 1, 64);
                v += __shfl_xor(v, 2, 64);
                v += __shfl_xor(v, 4, 64);
                v += __shfl_xor(v, 8, 64);
                if (c == 0) sPartial[s & 1][g*4 + q][u] = v;
            }
            if (s == 0 && st) {
#pragma unroll
                for (int n = 0; n < 3; ++n) *(unsigned short*)(sXwr + wbo + offD[n]) = bf16rne(sv[n]);
                if (sli < 8) *(unsigned short*)(sXwr + wbo + offD[3]) = bf16rne(sv[3]);
            }
        }
    }
    __syncthreads();
    if (u == 0 && g == 0) {   // final pred (i = 47, parity 1)
        f32x4 pp = *(const f32x4*)&sPartial[1][c][0];
        float pred = pp[0] + pp[1] + pp[2] + pp[3] + fb;
        out[(size_t)(row0 + c)*T_DEC + (T_DEC - 1)] = pred;
    }
}

extern "C" void kernel_launch(void* const* d_in, const int* in_sizes, int n_in,
                              void* d_out, int out_size, void* d_ws, size_t ws_size,
                              hipStream_t stream)
{
    const float* prior   = (const float*)d_in[0];
    const float* teacher = (const float*)d_in[1];
    const float* eWih    = (const float*)d_in[2];
    const float* eWhh    = (const float*)d_in[3];
    const float* eBih    = (const float*)d_in[4];
    const float* eBhh    = (const float*)d_in[5];
    const float* dWih    = (const float*)d_in[6];
    const float* dWhh    = (const float*)d_in[7];
    const float* dBih    = (const float*)d_in[8];
    const float* dBhh    = (const float*)d_in[9];
    const float* fcW     = (const float*)d_in[10];
    const float* fcB     = (const float*)d_in[11];
    float* out = (float*)d_out;

    dim3 grid(BATCH / 16);    // 512 blocks x 4 waves (full-K per wave, 1 barrier/step)
    dim3 block(256);
    hipLaunchKernelGGL(gru_mfma, grid, block, 0, stream,
                       prior, teacher, eWih, eWhh, eBih, eBhh,
                       dWih, dWhh, dBih, dBhh, fcW, fcB, out);
}

// Round 15
// 154.343 us; speedup vs baseline: 1.8571x; 1.0107x over previous
//
#include <hip/hip_runtime.h>
#include <hip/hip_bf16.h>

#define T_PRIOR 168
#define N_FEAT 11
#define DEC_FEAT 7
#define T_DEC 48
#define BATCH 8192
#define XROWU 136                // ushorts per staged row: 8 slots x 16 + 8-ushort zero pad (272 B)
#define ROWB (XROWU*2)           // 272 B
#define BUFB (16*ROWB)           // 4352 B per chunk buffer

typedef __attribute__((ext_vector_type(8))) short short8;
typedef __attribute__((ext_vector_type(4))) float f32x4;
typedef __attribute__((ext_vector_type(4))) int i32x4;

#define MFMA __builtin_amdgcn_mfma_f32_16x16x32_bf16

static __device__ __forceinline__ unsigned fbits(float f){union{float f;unsigned u;}v;v.f=f;return v.u;}
static __device__ __forceinline__ unsigned short bf16rne(float f){
    unsigned x=fbits(f);
    return (unsigned short)((x+0x7fffu+((x>>16)&1u))>>16);
}
static __device__ __forceinline__ float sigm(float x){ return __builtin_amdgcn_rcpf(1.0f + __expf(-x)); }
static __device__ __forceinline__ float tanhf_(float x){ return fmaf(2.0f, __builtin_amdgcn_rcpf(1.0f + __expf(-2.0f*x)), -1.0f); }
static __device__ __forceinline__ short8 s8(i32x4 v){union{i32x4 i;short8 s;}q;q.i=v;return q.s;}
// pack 2 f32 -> 2 bf16 (RNE) in one dword: compiler emits v_cvt_pk_bf16_f32
static __device__ __forceinline__ unsigned pk2bf(float a, float b){
    __hip_bfloat162 p = __float22bfloat162_rn(make_float2(a, b));
    union { __hip_bfloat162 h; unsigned u; } cv; cv.h = p; return cv.u;   // low16 = a, high16 = b
}

__global__ __launch_bounds__(256) __attribute__((amdgpu_waves_per_eu(2,2)))
void gru_mfma(const float* __restrict__ prior, const float* __restrict__ teacher,
              const float* __restrict__ eWih, const float* __restrict__ eWhh,
              const float* __restrict__ eBih, const float* __restrict__ eBhh,
              const float* __restrict__ dWih, const float* __restrict__ dWhh,
              const float* __restrict__ dBih, const float* __restrict__ dBhh,
              const float* __restrict__ fcW, const float* __restrict__ fcB,
              float* __restrict__ out)
{
    __shared__ __align__(16) unsigned short sH[2][1024];   // [parity][16 rows x 64 units] bf16, identity-kappa, swizzled
    __shared__ __align__(16) unsigned short sX[2*16*XROWU];// staged bf16 inputs, chunk dbuf
    __shared__ __align__(16) float sPartial[2][16][4];     // [parity][row][u]

    const int tid  = (int)threadIdx.x;
    const int lane = tid & 63;
    const int u    = tid >> 6;       // wave = unit tile (full K per wave)
    const int c    = lane & 15;      // batch row / B col
    const int g    = lane >> 4;      // k-group
    const int row0 = (int)blockIdx.x * 16;

    // ---- sH offsets: identity kappa (unit n at byte 2n ^ swz(row)) ----
    // reads: unchanged addresses from R13/R14 (B-packing re-indexed instead)
    const unsigned cs = ((unsigned)(c & 7)) << 4;
    const unsigned rbA0 = (unsigned)(c*128) + (((unsigned)(g*16)) ^ cs);       // units 0..31 chunk
    const unsigned rbA1 = (unsigned)(c*128) + (((unsigned)(64 + g*16)) ^ cs);  // units 32..63 chunk
    // writes: unit u*16+c -> byte 2*(u*16+c) = 32u+2c (bank-spread across the wave)
    unsigned pubOff[4];
#pragma unroll
    for (int q = 0; q < 4; ++q) {
        int r = g*4 + q;
        pubOff[q] = (unsigned)(r*128) + (((unsigned)(32*u + 2*c)) ^ (((unsigned)(r&7))<<4));
    }

    // ---- x read offsets: g-groups beyond the valid features read the zeroed 16B row pad ----
    const unsigned xRowB = (unsigned)(c*ROWB);
    const unsigned xE_off = (g < 2) ? (unsigned)(g*16) : 256u;
    const unsigned xE_mul = (g < 2) ? 32u : 0u;
    const unsigned xD_off = (g == 0) ? 0u : 256u;
    const unsigned xD_mul = (g == 0) ? 32u : 0u;
    char* sXB = (char*)sX;

    // ---- staging setup (all 256 threads) ----
    const int srow = tid >> 4, sli = tid & 15;
    char* sXwr = sXB + srow*ROWB;
    int offE[6], offD[4];
#pragma unroll
    for (int n = 0; n < 6; ++n) { int k = sli + 16*n; offE[n] = ((k/11)*16 + (k%11))*2; }
#pragma unroll
    for (int n = 0; n < 4; ++n) { int k = sli + 16*n; offD[n] = ((k/7)*16 + (k%7))*2; }
    const float* gP = prior   + (size_t)(row0 + srow)*(T_PRIOR*N_FEAT) + sli;
    const float* gT = teacher + (size_t)(row0 + srow)*(T_DEC*DEC_FEAT) + sli;

    // ---- per-wave weights (full K, single bf16; identity kappa) ----
    short8 BHH[3][2], BIH[3];
    f32x4 bR4, bZ4, bH4, bI4;
    auto loadPhase = [&](const float* Wih, const float* Whh,
                         const float* bih, const float* bhh, int kvalid) {
        const int rwb = u*16 + c;
#pragma unroll
        for (int gate = 0; gate < 3; ++gate) {
            const int rw = gate*64 + rwb;
#pragma unroll
            for (int kt = 0; kt < 2; ++kt) {
                union { short8 v; unsigned short s[8]; } fh;
#pragma unroll
                for (int j = 0; j < 8; ++j) {
                    int kap = kt*32 + g*8 + j;          // identity kappa: unit == k-slot
                    fh.s[j] = bf16rne(Whh[rw*64 + kap]);
                }
                BHH[gate][kt] = fh.v;
            }
            union { short8 v; unsigned short s[8]; } fi;
#pragma unroll
            for (int j = 0; j < 8; ++j) {
                int k = g*8 + j;
                fi.s[j] = (k < kvalid) ? bf16rne(Wih[rw*kvalid + k]) : (unsigned short)0;
            }
            BIH[gate] = fi.v;
        }
        const int un = u*16 + c;
        float vR = bih[un] + bhh[un];
        float vZ = bih[64+un] + bhh[64+un];
        float vI = bih[128+un];
        float vH = bhh[128+un];
        bR4 = (f32x4){vR,vR,vR,vR};
        bZ4 = (f32x4){vZ,vZ,vZ,vZ};
        bH4 = (f32x4){vH,vH,vH,vH};
        bI4 = (f32x4){vI,vI,vI,vI};
    };

    float h[4] = {0.0f, 0.0f, 0.0f, 0.0f};

    // gates + h update + publish (cvt_pk pair conversion, 4 b16 writes)
    auto gates_publish = [&](int p, f32x4 R, f32x4 Z, f32x4 Hh, f32x4 I) {
        char* hw = (char*)&sH[p^1][0];
        float hn[4];
#pragma unroll
        for (int q = 0; q < 4; ++q) {
            float rr = sigm(R[q]);
            float zz = sigm(Z[q]);
            float nn = tanhf_(fmaf(rr, Hh[q], I[q]));
            hn[q] = nn + zz*(h[q] - nn);
            h[q] = hn[q];
        }
        unsigned w01 = pk2bf(hn[0], hn[1]);
        unsigned w23 = pk2bf(hn[2], hn[3]);
        *(unsigned short*)(hw + pubOff[0]) = (unsigned short)(w01 & 0xffffu);
        *(unsigned short*)(hw + pubOff[1]) = (unsigned short)(w01 >> 16);
        *(unsigned short*)(hw + pubOff[2]) = (unsigned short)(w23 & 0xffffu);
        *(unsigned short*)(hw + pubOff[3]) = (unsigned short)(w23 >> 16);
    };

    // hoisted x-part: 3 MFMAs with bias C-in, independent of sH (issued pre-barrier)
    f32x4 xR, xZ, xI;
    auto xpart = [&](short8 xf) {
        xR = MFMA(xf, BIH[0], bR4, 0,0,0);
        xZ = MFMA(xf, BIH[1], bZ4, 0,0,0);
        xI = MFMA(xf, BIH[2], bI4, 0,0,0);
    };

    // post-barrier: 2 ds_read + 6 hh-MFMAs (C-in = hoisted x-part), gates, publish
    auto hh_step = [&](int p) {
        const char* hb = (const char*)&sH[p][0];
        short8 a0 = *(const short8*)(hb + rbA0);
        short8 a1 = *(const short8*)(hb + rbA1);
        __builtin_amdgcn_s_setprio(1);
        f32x4 R = MFMA(a0, BHH[0][0], xR, 0,0,0);
        R = MFMA(a1, BHH[0][1], R, 0,0,0);
        f32x4 Z = MFMA(a0, BHH[1][0], xZ, 0,0,0);
        Z = MFMA(a1, BHH[1][1], Z, 0,0,0);
        f32x4 Hh = MFMA(a0, BHH[2][0], bH4, 0,0,0);
        Hh = MFMA(a1, BHH[2][1], Hh, 0,0,0);
        __builtin_amdgcn_s_setprio(0);
        gates_publish(p, R, Z, Hh, xI);
    };

    // full 9-MFMA step (decoder path: x MFMAs post-barrier, after pred patch)
    auto gru_step = [&](int p, short8 xf) {
        const char* hb = (const char*)&sH[p][0];
        short8 a0 = *(const short8*)(hb + rbA0);
        short8 a1 = *(const short8*)(hb + rbA1);
        f32x4 R = MFMA(a0, BHH[0][0], bR4, 0,0,0);
        R = MFMA(a1, BHH[0][1], R, 0,0,0);
        R = MFMA(xf, BIH[0],    R, 0,0,0);
        f32x4 Z = MFMA(a0, BHH[1][0], bZ4, 0,0,0);
        Z = MFMA(a1, BHH[1][1], Z, 0,0,0);
        Z = MFMA(xf, BIH[1],    Z, 0,0,0);
        f32x4 Hh = MFMA(a0, BHH[2][0], bH4, 0,0,0);
        Hh = MFMA(a1, BHH[2][1], Hh, 0,0,0);
        f32x4 I = MFMA(xf, BIH[2], bI4, 0,0,0);
        gates_publish(p, R, Z, Hh, I);
    };

    // ---------------- prologue ----------------
    {   // h(0) = 0 into parity-0 buffer
        unsigned* z0 = (unsigned*)&sH[0][0];
#pragma unroll
        for (int it = 0; it < 2; ++it) z0[tid + 256*it] = 0u;
    }
    // zero encoder pad ushorts: f=11..15 per slot (640/buf) + row pad 128..135 (128/buf), both buffers
#pragma unroll
    for (int it = 0; it < 6; ++it) {
        int e = tid + 256*it;
        int b = e / 768, rem = e % 768;
        int idx;
        if (rem < 640) {
            int r = rem / 40, q2 = rem % 40;
            idx = b*(16*XROWU) + r*XROWU + (q2/5)*16 + 11 + q2%5;
        } else {
            int rem2 = rem - 640;
            idx = b*(16*XROWU) + (rem2 >> 3)*XROWU + 128 + (rem2 & 7);
        }
        sX[idx] = 0;
    }
    loadPhase(eWih, eWhh, eBih, eBhh, N_FEAT);
    {   // stage encoder chunk 0 (bf16)
        float sv[6];
#pragma unroll
        for (int n = 0; n < 5; ++n) sv[n] = gP[16*n];
        sv[5] = (sli < 8) ? gP[80] : 0.0f;
#pragma unroll
        for (int n = 0; n < 5; ++n) *(unsigned short*)(sXwr + offE[n]) = bf16rne(sv[n]);
        if (sli < 8) *(unsigned short*)(sXwr + offE[5]) = bf16rne(sv[5]);
    }
    __syncthreads();   // chunk-0 visible before the xf(0) prefetch read
    {
        short8 xf0 = *(const short8*)(sXB + (xRowB + xE_off));
        xpart(xf0);
    }

    // ---------------- encoder: 21 chunks x 8 steps, x-part hoisted ----------------
    for (int ch = 0; ch < 21; ++ch) {
        const unsigned wbo = (unsigned)(((ch + 1) & 1) * BUFB);
        const bool st = (ch < 20);
        float sv[6];
#pragma unroll
        for (int s = 0; s < 8; ++s) {
            const int t = ch*8 + s;
            __syncthreads();
            if (s == 0 && st) {              // issue next-chunk loads (full-chunk latency cover)
                const float* sp = gP + 88*(ch+1);
#pragma unroll
                for (int n = 0; n < 5; ++n) sv[n] = sp[16*n];
                sv[5] = (sli < 8) ? sp[80] : 0.0f;
            }
            hh_step(t & 1);                  // critical path: 2 ds_read + 6 MFMA + gates
            if (s == 0 && st) {              // write staged chunk to the other buffer
#pragma unroll
                for (int n = 0; n < 5; ++n) *(unsigned short*)(sXwr + wbo + offE[n]) = bf16rne(sv[n]);
                if (sli < 8) *(unsigned short*)(sXwr + wbo + offE[5]) = bf16rne(sv[5]);
            }
            if (t < T_PRIOR - 1) {           // prefetch x(t+1) + hoisted x-MFMAs (pre-barrier)
                const int tn = t + 1;
                const unsigned nbo = (unsigned)(((tn >> 3) & 1) * BUFB);
                short8 xf = *(const short8*)(sXB + (nbo + xRowB + xE_off + (unsigned)(tn & 7)*xE_mul));
                xpart(xf);
            }
        }
    }

    // ---------------- decoder setup ----------------
    __syncthreads();   // all encoder sX reads done before pad rewrites
    loadPhase(dWih, dWhh, dBih, dBhh, DEC_FEAT);
    const float fwc = fcW[u*16 + c];
    const float fb  = fcB[0];
    // zero decoder pad ushorts f=7..15 (1152/buf), both buffers
#pragma unroll
    for (int it = 0; it < 9; ++it) {
        int e = tid + 256*it;
        int b = e / 1152, rem = e % 1152;
        int r = rem / 72, q2 = rem % 72;
        sX[b*(16*XROWU) + r*XROWU + (q2/9)*16 + 7 + q2%9] = 0;
    }
    {   // stage decoder chunk 0
        float sv[4];
#pragma unroll
        for (int n = 0; n < 3; ++n) sv[n] = gT[16*n];
        sv[3] = (sli < 8) ? gT[48] : 0.0f;
#pragma unroll
        for (int n = 0; n < 3; ++n) *(unsigned short*)(sXwr + offD[n]) = bf16rne(sv[n]);
        if (sli < 8) *(unsigned short*)(sXwr + offD[3]) = bf16rne(sv[3]);
    }

    // ---------------- decoder: 6 chunks x 8 steps ----------------
    for (int ch = 0; ch < 6; ++ch) {
        const unsigned bo  = (unsigned)((ch & 1) * BUFB);
        const unsigned wbo = (unsigned)(((ch + 1) & 1) * BUFB);
        const bool st = (ch < 5);
        float sv[4];
#pragma unroll
        for (int s = 0; s < 8; ++s) {
            const int i = ch*8 + s;
            __syncthreads();
            if (s == 0 && st) {
                const float* sp = gT + 56*(ch+1);
#pragma unroll
                for (int n = 0; n < 3; ++n) sv[n] = sp[16*n];
                sv[3] = (sli < 8) ? sp[48] : 0.0f;
            }
            const bool hasPred = (s > 0) || (ch > 0);
            i32x4 xi = *(const i32x4*)(sXB + (bo + xRowB + xD_off + (unsigned)s*xD_mul));
            if (hasPred) {                    // pred_{i-1} from parity (s&1)^1 partials
                f32x4 pp = *(const f32x4*)&sPartial[(s & 1) ^ 1][c][0];
                float pred = pp[0] + pp[1] + pp[2] + pp[3] + fb;
                if (g == 0)                   // feature 4 = ushort #4 = word2 low half
                    xi[2] = (int)(((unsigned)xi[2] & 0xffff0000u) | (unsigned)bf16rne(pred));
                if (u == 0 && g == 0)
                    out[(size_t)(row0 + c)*T_DEC + (i - 1)] = pred;
            }
            gru_step(s & 1, s8(xi));
            // fc partials over this wave's 16 units
#pragma unroll
            for (int q = 0; q < 4; ++q) {
                float v = h[q] * fwc;
                v += __shfl_xor(v, 1, 64);
                v += __shfl_xor(v, 2, 64);
                v += __shfl_xor(v, 4, 64);
                v += __shfl_xor(v, 8, 64);
                if (c == 0) sPartial[s & 1][g*4 + q][u] = v;
            }
            if (s == 0 && st) {
#pragma unroll
                for (int n = 0; n < 3; ++n) *(unsigned short*)(sXwr + wbo + offD[n]) = bf16rne(sv[n]);
                if (sli < 8) *(unsigned short*)(sXwr + wbo + offD[3]) = bf16rne(sv[3]);
            }
        }
    }
    __syncthreads();
    if (u == 0 && g == 0) {   // final pred (i = 47, parity 1)
        f32x4 pp = *(const f32x4*)&sPartial[1][c][0];
        float pred = pp[0] + pp[1] + pp[2] + pp[3] + fb;
        out[(size_t)(row0 + c)*T_DEC + (T_DEC - 1)] = pred;
    }
}

extern "C" void kernel_launch(void* const* d_in, const int* in_sizes, int n_in,
                              void* d_out, int out_size, void* d_ws, size_t ws_size,
                              hipStream_t stream)
{
    const float* prior   = (const float*)d_in[0];
    const float* teacher = (const float*)d_in[1];
    const float* eWih    = (const float*)d_in[2];
    const float* eWhh    = (const float*)d_in[3];
    const float* eBih    = (const float*)d_in[4];
    const float* eBhh    = (const float*)d_in[5];
    const float* dWih    = (const float*)d_in[6];
    const float* dWhh    = (const float*)d_in[7];
    const float* dBih    = (const float*)d_in[8];
    const float* dBhh    = (const float*)d_in[9];
    const float* fcW     = (const float*)d_in[10];
    const float* fcB     = (const float*)d_in[11];
    float* out = (float*)d_out;

    dim3 grid(BATCH / 16);    // 512 blocks x 4 waves (full-K per wave, 1 barrier/step)
    dim3 block(256);
    hipLaunchKernelGGL(gru_mfma, grid, block, 0, stream,
                       prior, teacher, eWih, eWhh, eBih, eBhh,
                       dWih, dWhh, dBih, dBhh, fcW, fcB, out);
}

// Round 16
// 142.618 us; speedup vs baseline: 2.0097x; 1.0822x over previous
//
#include <hip/hip_runtime.h>
#include <hip/hip_bf16.h>

#define T_PRIOR 168
#define N_FEAT 11
#define DEC_FEAT 7
#define T_DEC 48
#define BATCH 8192
#define XROWU 136                // ushorts per staged row: 8 slots x 16 + 8-ushort zero pad (272 B)
#define ROWB (XROWU*2)           // 272 B
#define BUFB (16*ROWB)           // 4352 B per chunk buffer

typedef __attribute__((ext_vector_type(8))) short short8;
typedef __attribute__((ext_vector_type(4))) float f32x4;
typedef __attribute__((ext_vector_type(4))) int i32x4;

#define MFMA __builtin_amdgcn_mfma_f32_16x16x32_bf16
#define L2E 1.4426950408889634f   // log2(e); gates run in exp2 domain (weights pre-scaled)

static __device__ __forceinline__ unsigned fbits(float f){union{float f;unsigned u;}v;v.f=f;return v.u;}
static __device__ __forceinline__ unsigned short bf16rne(float f){
    unsigned x=fbits(f);
    return (unsigned short)((x+0x7fffu+((x>>16)&1u))>>16);
}
// exp2-domain gates: input is preact * log2e (r,z) or preact * 2*log2e (n).
// exp2f(-xs) folds the negation into the v_exp_f32 input modifier -> 1 trans inst, 0 muls.
static __device__ __forceinline__ float sigm2(float xs){
    return __builtin_amdgcn_rcpf(1.0f + __builtin_amdgcn_exp2f(-xs));
}
static __device__ __forceinline__ float tanh2(float ys){   // ys = 2*log2e*y
    return fmaf(2.0f, __builtin_amdgcn_rcpf(1.0f + __builtin_amdgcn_exp2f(-ys)), -1.0f);
}
static __device__ __forceinline__ short8 s8(i32x4 v){union{i32x4 i;short8 s;}q;q.i=v;return q.s;}
// pack 2 f32 -> 2 bf16 (RNE) in one dword (v_cvt_pk_bf16_f32)
static __device__ __forceinline__ unsigned pk2bf(float a, float b){
    __hip_bfloat162 p = __float22bfloat162_rn(make_float2(a, b));
    union { __hip_bfloat162 h; unsigned u; } cv; cv.h = p; return cv.u;   // low16 = a, high16 = b
}

__global__ __launch_bounds__(256) __attribute__((amdgpu_waves_per_eu(2,2)))
void gru_mfma(const float* __restrict__ prior, const float* __restrict__ teacher,
              const float* __restrict__ eWih, const float* __restrict__ eWhh,
              const float* __restrict__ eBih, const float* __restrict__ eBhh,
              const float* __restrict__ dWih, const float* __restrict__ dWhh,
              const float* __restrict__ dBih, const float* __restrict__ dBhh,
              const float* __restrict__ fcW, const float* __restrict__ fcB,
              float* __restrict__ out)
{
    __shared__ __align__(16) unsigned short sH[2][1024];   // [parity][16 rows x 64 units] bf16, identity-kappa, swizzled
    __shared__ __align__(16) unsigned short sX[2*16*XROWU];// staged bf16 inputs, chunk dbuf
    __shared__ __align__(16) float sPartial[2][16][4];     // [parity][row][u]

    const int tid  = (int)threadIdx.x;
    const int lane = tid & 63;
    const int u    = tid >> 6;       // wave = unit tile (full K per wave)
    const int c    = lane & 15;      // batch row / B col
    const int g    = lane >> 4;      // k-group
    const int row0 = (int)blockIdx.x * 16;

    // ---- sH offsets (identity kappa, XOR-swizzled; R15-proven) ----
    const unsigned cs = ((unsigned)(c & 7)) << 4;
    const unsigned rbA0 = (unsigned)(c*128) + (((unsigned)(g*16)) ^ cs);       // units 0..31
    const unsigned rbA1 = (unsigned)(c*128) + (((unsigned)(64 + g*16)) ^ cs);  // units 32..63
    unsigned pubOff[4];
#pragma unroll
    for (int q = 0; q < 4; ++q) {
        int r = g*4 + q;
        pubOff[q] = (unsigned)(r*128) + (((unsigned)(32*u + 2*c)) ^ (((unsigned)(r&7))<<4));
    }

    // ---- x read offsets: g-groups beyond the valid features read the zeroed 16B row pad ----
    const unsigned xRowB = (unsigned)(c*ROWB);
    const unsigned xE_off = (g < 2) ? (unsigned)(g*16) : 256u;
    const unsigned xE_mul = (g < 2) ? 32u : 0u;
    const unsigned xD_off = (g == 0) ? 0u : 256u;
    const unsigned xD_mul = (g == 0) ? 32u : 0u;
    char* sXB = (char*)sX;

    // ---- staging setup (all 256 threads) ----
    const int srow = tid >> 4, sli = tid & 15;
    char* sXwr = sXB + srow*ROWB;
    int offE[6], offD[4];
#pragma unroll
    for (int n = 0; n < 6; ++n) { int k = sli + 16*n; offE[n] = ((k/11)*16 + (k%11))*2; }
#pragma unroll
    for (int n = 0; n < 4; ++n) { int k = sli + 16*n; offD[n] = ((k/7)*16 + (k%7))*2; }
    const float* gP = prior   + (size_t)(row0 + srow)*(T_PRIOR*N_FEAT) + sli;
    const float* gT = teacher + (size_t)(row0 + srow)*(T_DEC*DEC_FEAT) + sli;

    // ---- per-wave weights (full K, single bf16; identity kappa; exp2-domain scaling) ----
    short8 BHH[3][2], BIH[3];
    f32x4 bR4, bZ4, bH4, bI4;
    auto loadPhase = [&](const float* Wih, const float* Whh,
                         const float* bih, const float* bhh, int kvalid) {
        const int rwb = u*16 + c;
#pragma unroll
        for (int gate = 0; gate < 3; ++gate) {
            const float gs = (gate == 2) ? (2.0f*L2E) : L2E;   // n-gate: tanh(y)=2sig(2y)-1
            const int rw = gate*64 + rwb;
#pragma unroll
            for (int kt = 0; kt < 2; ++kt) {
                union { short8 v; unsigned short s[8]; } fh;
#pragma unroll
                for (int j = 0; j < 8; ++j) {
                    int kap = kt*32 + g*8 + j;          // identity kappa: unit == k-slot
                    fh.s[j] = bf16rne(Whh[rw*64 + kap] * gs);
                }
                BHH[gate][kt] = fh.v;
            }
            union { short8 v; unsigned short s[8]; } fi;
#pragma unroll
            for (int j = 0; j < 8; ++j) {
                int k = g*8 + j;
                fi.s[j] = (k < kvalid) ? bf16rne(Wih[rw*kvalid + k] * gs) : (unsigned short)0;
            }
            BIH[gate] = fi.v;
        }
        const int un = u*16 + c;
        float vR = (bih[un] + bhh[un]) * L2E;
        float vZ = (bih[64+un] + bhh[64+un]) * L2E;
        float vI = bih[128+un] * (2.0f*L2E);
        float vH = bhh[128+un] * (2.0f*L2E);
        bR4 = (f32x4){vR,vR,vR,vR};
        bZ4 = (f32x4){vZ,vZ,vZ,vZ};
        bH4 = (f32x4){vH,vH,vH,vH};
        bI4 = (f32x4){vI,vI,vI,vI};
    };

    float h[4] = {0.0f, 0.0f, 0.0f, 0.0f};

    // gates (exp2 domain) + h update + publish (cvt_pk, 4 b16 writes)
    auto gates_publish = [&](int p, f32x4 R, f32x4 Z, f32x4 Hh, f32x4 I) {
        char* hw = (char*)&sH[p^1][0];
        float hn[4];
#pragma unroll
        for (int q = 0; q < 4; ++q) {
            float rr = sigm2(R[q]);
            float zz = sigm2(Z[q]);
            float nn = tanh2(fmaf(rr, Hh[q], I[q]));   // Hh, I carry the 2*log2e factor
            hn[q] = nn + zz*(h[q] - nn);
            h[q] = hn[q];
        }
        unsigned w01 = pk2bf(hn[0], hn[1]);
        unsigned w23 = pk2bf(hn[2], hn[3]);
        *(unsigned short*)(hw + pubOff[0]) = (unsigned short)(w01 & 0xffffu);
        *(unsigned short*)(hw + pubOff[1]) = (unsigned short)(w01 >> 16);
        *(unsigned short*)(hw + pubOff[2]) = (unsigned short)(w23 & 0xffffu);
        *(unsigned short*)(hw + pubOff[3]) = (unsigned short)(w23 >> 16);
    };

    // hoisted x-part: 3 MFMAs with bias C-in, independent of sH (issued pre-barrier)
    f32x4 xR, xZ, xI;
    auto xpart = [&](short8 xf) {
        xR = MFMA(xf, BIH[0], bR4, 0,0,0);
        xZ = MFMA(xf, BIH[1], bZ4, 0,0,0);
        xI = MFMA(xf, BIH[2], bI4, 0,0,0);
    };

    // post-barrier: 2 ds_read + 6 hh-MFMAs (C-in = hoisted x-part), gates, publish
    auto hh_step = [&](int p) {
        const char* hb = (const char*)&sH[p][0];
        short8 a0 = *(const short8*)(hb + rbA0);
        short8 a1 = *(const short8*)(hb + rbA1);
        __builtin_amdgcn_s_setprio(1);
        f32x4 R = MFMA(a0, BHH[0][0], xR, 0,0,0);
        R = MFMA(a1, BHH[0][1], R, 0,0,0);
        f32x4 Z = MFMA(a0, BHH[1][0], xZ, 0,0,0);
        Z = MFMA(a1, BHH[1][1], Z, 0,0,0);
        f32x4 Hh = MFMA(a0, BHH[2][0], bH4, 0,0,0);
        Hh = MFMA(a1, BHH[2][1], Hh, 0,0,0);
        __builtin_amdgcn_s_setprio(0);
        gates_publish(p, R, Z, Hh, xI);
    };

    // full 9-MFMA step (decoder path: x MFMAs post-barrier, after pred patch)
    auto gru_step = [&](int p, short8 xf) {
        const char* hb = (const char*)&sH[p][0];
        short8 a0 = *(const short8*)(hb + rbA0);
        short8 a1 = *(const short8*)(hb + rbA1);
        f32x4 R = MFMA(a0, BHH[0][0], bR4, 0,0,0);
        R = MFMA(a1, BHH[0][1], R, 0,0,0);
        R = MFMA(xf, BIH[0],    R, 0,0,0);
        f32x4 Z = MFMA(a0, BHH[1][0], bZ4, 0,0,0);
        Z = MFMA(a1, BHH[1][1], Z, 0,0,0);
        Z = MFMA(xf, BIH[1],    Z, 0,0,0);
        f32x4 Hh = MFMA(a0, BHH[2][0], bH4, 0,0,0);
        Hh = MFMA(a1, BHH[2][1], Hh, 0,0,0);
        f32x4 I = MFMA(xf, BIH[2], bI4, 0,0,0);
        gates_publish(p, R, Z, Hh, I);
    };

    // ---------------- prologue ----------------
    {   // h(0) = 0 into parity-0 buffer
        unsigned* z0 = (unsigned*)&sH[0][0];
#pragma unroll
        for (int it = 0; it < 2; ++it) z0[tid + 256*it] = 0u;
    }
    // zero encoder pad ushorts: f=11..15 per slot (640/buf) + row pad 128..135 (128/buf), both buffers
#pragma unroll
    for (int it = 0; it < 6; ++it) {
        int e = tid + 256*it;
        int b = e / 768, rem = e % 768;
        int idx;
        if (rem < 640) {
            int r = rem / 40, q2 = rem % 40;
            idx = b*(16*XROWU) + r*XROWU + (q2/5)*16 + 11 + q2%5;
        } else {
            int rem2 = rem - 640;
            idx = b*(16*XROWU) + (rem2 >> 3)*XROWU + 128 + (rem2 & 7);
        }
        sX[idx] = 0;
    }
    loadPhase(eWih, eWhh, eBih, eBhh, N_FEAT);
    {   // stage encoder chunk 0 (bf16)
        float sv[6];
#pragma unroll
        for (int n = 0; n < 5; ++n) sv[n] = gP[16*n];
        sv[5] = (sli < 8) ? gP[80] : 0.0f;
#pragma unroll
        for (int n = 0; n < 5; ++n) *(unsigned short*)(sXwr + offE[n]) = bf16rne(sv[n]);
        if (sli < 8) *(unsigned short*)(sXwr + offE[5]) = bf16rne(sv[5]);
    }
    __syncthreads();   // chunk-0 visible before the xf(0) prefetch read
    {
        short8 xf0 = *(const short8*)(sXB + (xRowB + xE_off));
        xpart(xf0);
    }

    // ---------------- encoder: 21 chunks x 8 steps ----------------
    // loads issued at s==0; LDS write DEFERRED to end of s==1 (~2 steps of vmcnt cover)
    for (int ch = 0; ch < 21; ++ch) {
        const unsigned wbo = (unsigned)(((ch + 1) & 1) * BUFB);
        const bool st = (ch < 20);
        float sv[6];
#pragma unroll
        for (int s = 0; s < 8; ++s) {
            const int t = ch*8 + s;
            __syncthreads();
            if (s == 0 && st) {              // issue next-chunk loads
                const float* sp = gP + 88*(ch+1);
#pragma unroll
                for (int n = 0; n < 5; ++n) sv[n] = sp[16*n];
                sv[5] = (sli < 8) ? sp[80] : 0.0f;
            }
            hh_step(t & 1);                  // critical path: 2 ds_read + 6 MFMA + gates
            if (s == 1 && st) {              // deferred staged write (loads long landed)
#pragma unroll
                for (int n = 0; n < 5; ++n) *(unsigned short*)(sXwr + wbo + offE[n]) = bf16rne(sv[n]);
                if (sli < 8) *(unsigned short*)(sXwr + wbo + offE[5]) = bf16rne(sv[5]);
            }
            if (t < T_PRIOR - 1) {           // prefetch x(t+1) + hoisted x-MFMAs (pre-barrier)
                const int tn = t + 1;
                const unsigned nbo = (unsigned)(((tn >> 3) & 1) * BUFB);
                short8 xf = *(const short8*)(sXB + (nbo + xRowB + xE_off + (unsigned)(tn & 7)*xE_mul));
                xpart(xf);
            }
        }
    }

    // ---------------- decoder setup ----------------
    __syncthreads();   // all encoder sX reads done before pad rewrites
    loadPhase(dWih, dWhh, dBih, dBhh, DEC_FEAT);
    const float fwc = fcW[u*16 + c];
    const float fb  = fcB[0];
    // zero decoder pad ushorts f=7..15 (1152/buf), both buffers
#pragma unroll
    for (int it = 0; it < 9; ++it) {
        int e = tid + 256*it;
        int b = e / 1152, rem = e % 1152;
        int r = rem / 72, q2 = rem % 72;
        sX[b*(16*XROWU) + r*XROWU + (q2/9)*16 + 7 + q2%9] = 0;
    }
    {   // stage decoder chunk 0
        float sv[4];
#pragma unroll
        for (int n = 0; n < 3; ++n) sv[n] = gT[16*n];
        sv[3] = (sli < 8) ? gT[48] : 0.0f;
#pragma unroll
        for (int n = 0; n < 3; ++n) *(unsigned short*)(sXwr + offD[n]) = bf16rne(sv[n]);
        if (sli < 8) *(unsigned short*)(sXwr + offD[3]) = bf16rne(sv[3]);
    }

    // ---------------- decoder: 6 chunks x 8 steps (deferred staged write) ----------------
    for (int ch = 0; ch < 6; ++ch) {
        const unsigned bo  = (unsigned)((ch & 1) * BUFB);
        const unsigned wbo = (unsigned)(((ch + 1) & 1) * BUFB);
        const bool st = (ch < 5);
        float sv[4];
#pragma unroll
        for (int s = 0; s < 8; ++s) {
            const int i = ch*8 + s;
            __syncthreads();
            if (s == 0 && st) {
                const float* sp = gT + 56*(ch+1);
#pragma unroll
                for (int n = 0; n < 3; ++n) sv[n] = sp[16*n];
                sv[3] = (sli < 8) ? sp[48] : 0.0f;
            }
            const bool hasPred = (s > 0) || (ch > 0);
            i32x4 xi = *(const i32x4*)(sXB + (bo + xRowB + xD_off + (unsigned)s*xD_mul));
            if (hasPred) {                    // pred_{i-1} from parity (s&1)^1 partials
                f32x4 pp = *(const f32x4*)&sPartial[(s & 1) ^ 1][c][0];
                float pred = pp[0] + pp[1] + pp[2] + pp[3] + fb;
                if (g == 0)                   // feature 4 = ushort #4 = word2 low half
                    xi[2] = (int)(((unsigned)xi[2] & 0xffff0000u) | (unsigned)bf16rne(pred));
                if (u == 0 && g == 0)
                    out[(size_t)(row0 + c)*T_DEC + (i - 1)] = pred;
            }
            gru_step(s & 1, s8(xi));
            // fc partials over this wave's 16 units
#pragma unroll
            for (int q = 0; q < 4; ++q) {
                float v = h[q] * fwc;
                v += __shfl_xor(v, 1, 64);
                v += __shfl_xor(v, 2, 64);
                v += __shfl_xor(v, 4, 64);
                v += __shfl_xor(v, 8, 64);
                if (c == 0) sPartial[s & 1][g*4 + q][u] = v;
            }
            if (s == 1 && st) {               // deferred staged write
#pragma unroll
                for (int n = 0; n < 3; ++n) *(unsigned short*)(sXwr + wbo + offD[n]) = bf16rne(sv[n]);
                if (sli < 8) *(unsigned short*)(sXwr + wbo + offD[3]) = bf16rne(sv[3]);
            }
        }
    }
    __syncthreads();
    if (u == 0 && g == 0) {   // final pred (i = 47, parity 1)
        f32x4 pp = *(const f32x4*)&sPartial[1][c][0];
        float pred = pp[0] + pp[1] + pp[2] + pp[3] + fb;
        out[(size_t)(row0 + c)*T_DEC + (T_DEC - 1)] = pred;
    }
}

extern "C" void kernel_launch(void* const* d_in, const int* in_sizes, int n_in,
                              void* d_out, int out_size, void* d_ws, size_t ws_size,
                              hipStream_t stream)
{
    const float* prior   = (const float*)d_in[0];
    const float* teacher = (const float*)d_in[1];
    const float* eWih    = (const float*)d_in[2];
    const float* eWhh    = (const float*)d_in[3];
    const float* eBih    = (const float*)d_in[4];
    const float* eBhh    = (const float*)d_in[5];
    const float* dWih    = (const float*)d_in[6];
    const float* dWhh    = (const float*)d_in[7];
    const float* dBih    = (const float*)d_in[8];
    const float* dBhh    = (const float*)d_in[9];
    const float* fcW     = (const float*)d_in[10];
    const float* fcB     = (const float*)d_in[11];
    float* out = (float*)d_out;

    dim3 grid(BATCH / 16);    // 512 blocks x 4 waves (full-K per wave, 1 barrier/step)
    dim3 block(256);
    hipLaunchKernelGGL(gru_mfma, grid, block, 0, stream,
                       prior, teacher, eWih, eWhh, eBih, eBhh,
                       dWih, dWhh, dBih, dBhh, fcW, fcB, out);
}